// Round 14
// baseline (139.285 us; speedup 1.0000x reference)
//
#include <hip/hip_runtime.h>

#define F_IN 128
#define F_H 64
#define F_OUT 16
#define RB 128           // nodes per bucket
#define RB_SHIFT 7       // bucket = dst >> 7
#define DBINS 64         // degree bins for bucket-local degree ranking
#define CAP 3072         // global bucket capacity (mean 2047, sigma 45)
#define LDSCAP 2816      // LDS sorted-edge capacity (mean + 17 sigma)
#define XSTR 136         // bf16 LDS row stride for gemm1 (16B-aligned b128)

typedef unsigned long long u64;
typedef unsigned int u32;
typedef unsigned short u16;
typedef __attribute__((ext_vector_type(8))) short short8;
typedef __attribute__((ext_vector_type(4))) float floatx4;

__device__ __forceinline__ u32 pack2bf16(float a, float b) {
    u32 ua = (__float_as_uint(a) + 0x8000u) >> 16;
    u32 ub = (__float_as_uint(b) + 0x8000u) & 0xFFFF0000u;
    return ua | ub;
}
__device__ __forceinline__ u16 bf16r(float a) {
    return (u16)((__float_as_uint(a) + 0x8000u) >> 16);
}

// ---------------------------------------------------------------------------
// GEMM1 (MFMA bf16): h1 sliced = x[N,128] @ W1[128,64]
// h1 layout: 4 planes of [N][8 u32] (16 feats/plane, bf16 pairs):
//   h1s[((p*N)+n)*8 + jj] holds feats 16p+2jj, 16p+2jj+1
// ---------------------------------------------------------------------------
__global__ __launch_bounds__(256) void gemm1_kernel(
    const float* __restrict__ x, const float* __restrict__ W,
    u32* __restrict__ h1s, int N) {
    __shared__ u16 sh[2 * 64 * XSTR];    // 34.8 KB: xls | w1t; reused as f32 stage
    u16* xls = sh;                       // [64][XSTR]  x tile bf16 [node][k]
    u16* w1t = sh + 64 * XSTR;           // [64][XSTR]  W1^T bf16 [col][k]
    float* stage = (float*)sh;           // [64][65] f32 C staging (epilogue)

    const int tid = threadIdx.x;
    const int n0 = blockIdx.x * 64;

    {   // load x tile -> bf16 LDS
        const int c4 = (tid & 31) * 4;
        const int r0 = tid >> 5;
        #pragma unroll
        for (int r = 0; r < 8; ++r) {
            const int row = r0 + r * 8;
            int n = n0 + row;
            if (n >= N) n = N - 1;
            const float4 v = *(const float4*)(x + (size_t)n * F_IN + c4);
            u16* p = &xls[row * XSTR + c4];
            p[0] = bf16r(v.x); p[1] = bf16r(v.y);
            p[2] = bf16r(v.z); p[3] = bf16r(v.w);
        }
    }
    {   // load W1 transposed -> bf16 LDS: w1t[col][k]
        const int k0 = tid >> 4;
        const int c4 = (tid & 15) * 4;
        #pragma unroll
        for (int r = 0; r < 8; ++r) {
            const int k = k0 + r * 16;
            const float4 v = *(const float4*)(W + (size_t)k * F_H + c4);
            w1t[(c4 + 0) * XSTR + k] = bf16r(v.x);
            w1t[(c4 + 1) * XSTR + k] = bf16r(v.y);
            w1t[(c4 + 2) * XSTR + k] = bf16r(v.z);
            w1t[(c4 + 3) * XSTR + k] = bf16r(v.w);
        }
    }
    __syncthreads();

    const int wv = tid >> 6;
    const int l = tid & 63;
    const int lr = l & 15;
    const int lk = (l >> 4) * 8;

    floatx4 acc[4] = {{0.f, 0.f, 0.f, 0.f}, {0.f, 0.f, 0.f, 0.f},
                      {0.f, 0.f, 0.f, 0.f}, {0.f, 0.f, 0.f, 0.f}};
    #pragma unroll
    for (int ks = 0; ks < 4; ++ks) {
        const short8 a = *(const short8*)&xls[(wv * 16 + lr) * XSTR + ks * 32 + lk];
        #pragma unroll
        for (int c = 0; c < 4; ++c) {
            const short8 bfr = *(const short8*)&w1t[(c * 16 + lr) * XSTR + ks * 32 + lk];
            acc[c] = __builtin_amdgcn_mfma_f32_16x16x32_bf16(a, bfr, acc[c], 0, 0, 0);
        }
    }
    __syncthreads();

    // C layout (verified): col = lane&15, row = (lane>>4)*4 + reg
    #pragma unroll
    for (int c = 0; c < 4; ++c) {
        #pragma unroll
        for (int r = 0; r < 4; ++r) {
            const int row = wv * 16 + (l >> 4) * 4 + r;
            stage[row * 65 + c * 16 + lr] = acc[c][r];
        }
    }
    __syncthreads();

    // pack f32 pairs -> bf16 u32, store into sliced planes
    #pragma unroll
    for (int t = 0; t < 8; ++t) {
        const int idx = t * 256 + tid;   // 0..2047
        const int row = idx >> 5, j = idx & 31;
        const int n = n0 + row;
        if (n < N) {
            const float f0 = stage[row * 65 + 2 * j];
            const float f1 = stage[row * 65 + 2 * j + 1];
            h1s[((size_t)(j >> 3) * N + n) * 8 + (j & 7)] = pack2bf16(f0, f1);
        }
    }
}

// ---------------------------------------------------------------------------
// fill: block-local counting sort into CAP-strided bucket-grouped edata1
// entry: [63:32]=weight f32 bits, [26:20]=dst&127, [19:0]=src
// ---------------------------------------------------------------------------
__global__ __launch_bounds__(1024) void fill_kernel(
    const int* __restrict__ src, const int* __restrict__ dst,
    const float* __restrict__ ew, int* __restrict__ gcur,
    u64* __restrict__ edata, int E, int nbuck) {
    __shared__ int cnt[800];
    __shared__ int base[800];
    int chunk = (E + gridDim.x - 1) / gridDim.x;
    chunk = (chunk + 3) & ~3;
    const int e0 = blockIdx.x * chunk;
    const int e1 = min(e0 + chunk, E);

    for (int i = threadIdx.x; i < nbuck; i += 1024) cnt[i] = 0;
    __syncthreads();

    int e = e0 + threadIdx.x * 4;
    for (; e + 3 < e1; e += 4096) {
        const int4 d4 = *(const int4*)(dst + e);
        atomicAdd(&cnt[d4.x >> RB_SHIFT], 1);
        atomicAdd(&cnt[d4.y >> RB_SHIFT], 1);
        atomicAdd(&cnt[d4.z >> RB_SHIFT], 1);
        atomicAdd(&cnt[d4.w >> RB_SHIFT], 1);
    }
    for (; e < e1; ++e) atomicAdd(&cnt[dst[e] >> RB_SHIFT], 1);
    __syncthreads();

    for (int i = threadIdx.x; i < nbuck; i += 1024) {
        const int c = cnt[i];
        base[i] = i * CAP + (c ? atomicAdd(&gcur[i], c) : 0);
        cnt[i] = 0;
    }
    __syncthreads();

    e = e0 + threadIdx.x * 4;
    for (; e + 3 < e1; e += 4096) {
        const int4 d4 = *(const int4*)(dst + e);
        const int4 s4 = *(const int4*)(src + e);
        const float4 w4 = *(const float4*)(ew + e);
        {
            const int b = d4.x >> RB_SHIFT;
            const int p = atomicAdd(&cnt[b], 1);
            edata[(size_t)base[b] + p] = ((u64)__float_as_uint(w4.x) << 32) |
                (u32)s4.x | ((u32)(d4.x & (RB - 1)) << 20);
        }
        {
            const int b = d4.y >> RB_SHIFT;
            const int p = atomicAdd(&cnt[b], 1);
            edata[(size_t)base[b] + p] = ((u64)__float_as_uint(w4.y) << 32) |
                (u32)s4.y | ((u32)(d4.y & (RB - 1)) << 20);
        }
        {
            const int b = d4.z >> RB_SHIFT;
            const int p = atomicAdd(&cnt[b], 1);
            edata[(size_t)base[b] + p] = ((u64)__float_as_uint(w4.z) << 32) |
                (u32)s4.z | ((u32)(d4.z & (RB - 1)) << 20);
        }
        {
            const int b = d4.w >> RB_SHIFT;
            const int p = atomicAdd(&cnt[b], 1);
            edata[(size_t)base[b] + p] = ((u64)__float_as_uint(w4.w) << 32) |
                (u32)s4.w | ((u32)(d4.w & (RB - 1)) << 20);
        }
    }
    for (; e < e1; ++e) {
        const int d = dst[e];
        const int b = d >> RB_SHIFT;
        const int p = atomicAdd(&cnt[b], 1);
        edata[(size_t)base[b] + p] = ((u64)__float_as_uint(ew[e]) << 32) |
            (u32)src[e] | ((u32)(d & (RB - 1)) << 20);
    }
}

// ---------------------------------------------------------------------------
// aggL1: one 1024-thread block per bucket.
//  1) counting-sort edges into LDS (esh); degree-rank nodes  (as R13)
//  2) 4 FEATURE-PLANE PASSES over the sorted esh: plane p (3.2 MB,
//     L2-resident) gathered by 8-lane groups (lane-pair = 32B slice,
//     4 edges in flight); butterfly shfl_xor combine; relu+pack -> stg
//  3) W2 pass (unchanged) -> h2b bf16
// ---------------------------------------------------------------------------
__global__ __launch_bounds__(1024) void aggL1_kernel(
    const u32* __restrict__ h1s, const u64* __restrict__ edata,
    const int* __restrict__ gcnt, const float* __restrict__ b1,
    const float* __restrict__ W2, u32* __restrict__ h2b, int N) {
    __shared__ u64 esh[LDSCAP];          // 22.5 KB sorted edges
    __shared__ u32 stg[RB * 32];         // 16 KB bf16 acc staging
    __shared__ float w2s[64 * 16];       // 4 KB
    __shared__ int cnt[RB];
    __shared__ int pref[RB];
    __shared__ int cur[RB];
    __shared__ int dbin[DBINS];
    __shared__ int dcur[DBINS];
    __shared__ int nodeOrder[RB];

    const int tid = threadIdx.x;
    const int b = blockIdx.x;
    const size_t s0 = (size_t)b * CAP;
    const int ecount = min(gcnt[b], LDSCAP);

    w2s[tid] = W2[tid];
    if (tid < RB) cnt[tid] = 0;
    if (tid < DBINS) dbin[tid] = 0;
    __syncthreads();

    for (int i = tid; i < ecount; i += 1024) {
        const int d = ((u32)edata[s0 + i] >> 20) & (RB - 1);
        atomicAdd(&cnt[d], 1);
    }
    __syncthreads();
    if (tid < RB) pref[tid] = cnt[tid];
    __syncthreads();
    for (int o = 1; o < RB; o <<= 1) {
        int v = 0;
        if (tid < RB && tid >= o) v = pref[tid - o];
        __syncthreads();
        if (tid < RB) pref[tid] += v;
        __syncthreads();
    }
    if (tid < RB) {
        cur[tid] = pref[tid] - cnt[tid];
        atomicAdd(&dbin[min(cnt[tid], DBINS - 1)], 1);
    }
    __syncthreads();
    if (tid < DBINS) dcur[tid] = dbin[tid];
    __syncthreads();
    for (int o = 1; o < DBINS; o <<= 1) {
        int v = 0;
        if (tid < DBINS && tid >= o) v = dcur[tid - o];
        __syncthreads();
        if (tid < DBINS) dcur[tid] += v;
        __syncthreads();
    }
    if (tid < DBINS) dcur[tid] -= dbin[tid];
    __syncthreads();
    if (tid < RB) {
        const int r = atomicAdd(&dcur[min(cnt[tid], DBINS - 1)], 1);
        nodeOrder[r] = tid;
    }
    for (int i = tid; i < ecount; i += 1024) {
        const u64 ed = edata[s0 + i];
        const int d = ((u32)ed >> 20) & (RB - 1);
        const int p = atomicAdd(&cur[d], 1);
        esh[p] = ed;
    }
    __syncthreads();

    // gather in 4 feature-plane passes
    const int g = tid >> 3;              // degree rank (one node per group)
    const int l = tid & 7;
    const int esub = l >> 1;             // edge slot 0..3
    const int half = l & 1;              // 16B half of the 32B slice
    const int ln = nodeOrder[g];
    const int end = pref[ln];
    const int beg = end - cnt[ln];

    #pragma unroll
    for (int p = 0; p < 4; ++p) {
        const u32* plane = h1s + (size_t)p * N * 8;
        float acc[8] = {0.f, 0.f, 0.f, 0.f, 0.f, 0.f, 0.f, 0.f};

        for (int i = beg; i < end; i += 8) {
            const int j0 = i + esub;
            const int j1 = i + 4 + esub;
            if (j0 < end) {
                const u64 e0 = esh[j0];
                const float w = __uint_as_float((u32)(e0 >> 32));
                const uint4 v = *(const uint4*)(plane + (size_t)((u32)e0 & 0xFFFFF) * 8 + half * 4);
                acc[0] += __uint_as_float(v.x << 16) * w;
                acc[1] += __uint_as_float(v.x & 0xFFFF0000u) * w;
                acc[2] += __uint_as_float(v.y << 16) * w;
                acc[3] += __uint_as_float(v.y & 0xFFFF0000u) * w;
                acc[4] += __uint_as_float(v.z << 16) * w;
                acc[5] += __uint_as_float(v.z & 0xFFFF0000u) * w;
                acc[6] += __uint_as_float(v.w << 16) * w;
                acc[7] += __uint_as_float(v.w & 0xFFFF0000u) * w;
            }
            if (j1 < end) {
                const u64 e1 = esh[j1];
                const float w = __uint_as_float((u32)(e1 >> 32));
                const uint4 v = *(const uint4*)(plane + (size_t)((u32)e1 & 0xFFFFF) * 8 + half * 4);
                acc[0] += __uint_as_float(v.x << 16) * w;
                acc[1] += __uint_as_float(v.x & 0xFFFF0000u) * w;
                acc[2] += __uint_as_float(v.y << 16) * w;
                acc[3] += __uint_as_float(v.y & 0xFFFF0000u) * w;
                acc[4] += __uint_as_float(v.z << 16) * w;
                acc[5] += __uint_as_float(v.z & 0xFFFF0000u) * w;
                acc[6] += __uint_as_float(v.w << 16) * w;
                acc[7] += __uint_as_float(v.w & 0xFFFF0000u) * w;
            }
        }
        // combine the 4 edge-slot lanes (same half)
        #pragma unroll
        for (int k = 0; k < 8; ++k) {
            acc[k] += __shfl_xor(acc[k], 2, 64);
            acc[k] += __shfl_xor(acc[k], 4, 64);
        }
        // bias + relu + pack; lanes with esub==0 write (one writer per half)
        if (esub == 0) {
            const float4 ba = *(const float4*)(b1 + p * 16 + half * 8);
            const float4 bb = *(const float4*)(b1 + p * 16 + half * 8 + 4);
            const float r0 = fmaxf(acc[0] + ba.x, 0.f);
            const float r1 = fmaxf(acc[1] + ba.y, 0.f);
            const float r2 = fmaxf(acc[2] + ba.z, 0.f);
            const float r3 = fmaxf(acc[3] + ba.w, 0.f);
            const float r4 = fmaxf(acc[4] + bb.x, 0.f);
            const float r5 = fmaxf(acc[5] + bb.y, 0.f);
            const float r6 = fmaxf(acc[6] + bb.z, 0.f);
            const float r7 = fmaxf(acc[7] + bb.w, 0.f);
            u32* sp = &stg[g * 32 + p * 8 + half * 4];
            sp[0] = pack2bf16(r0, r1);
            sp[1] = pack2bf16(r2, r3);
            sp[2] = pack2bf16(r4, r5);
            sp[3] = pack2bf16(r6, r7);
        }
    }
    __syncthreads();

    // W2 pass: slot s = tid>>3 (rank), col pair c = tid&7 (cols 2c, 2c+1)
    const int s = tid >> 3;
    const int c = tid & 7;
    float o0 = 0.f, o1 = 0.f;
    #pragma unroll 8
    for (int w = 0; w < 32; ++w) {       // u32 w covers feats 2w, 2w+1
        const u32 pw = stg[s * 32 + w];
        const float f0 = __uint_as_float(pw << 16);
        const float f1 = __uint_as_float(pw & 0xFFFF0000u);
        o0 += f0 * w2s[(2 * w) * 16 + 2 * c] + f1 * w2s[(2 * w + 1) * 16 + 2 * c];
        o1 += f0 * w2s[(2 * w) * 16 + 2 * c + 1] + f1 * w2s[(2 * w + 1) * 16 + 2 * c + 1];
    }
    const int gn = b * RB + nodeOrder[s];
    if (gn < N) h2b[(size_t)gn * 8 + c] = pack2bf16(o0, o1);
}

// ---------------------------------------------------------------------------
// aggL2: one 512-thread block per bucket. (unchanged from R13)
// ---------------------------------------------------------------------------
__global__ __launch_bounds__(512) void aggL2_kernel(
    const u32* __restrict__ h2b, const u64* __restrict__ edata,
    const int* __restrict__ gcnt, const float* __restrict__ b2,
    float* __restrict__ out, int N) {
    __shared__ u64 esh[LDSCAP];
    __shared__ int cnt[RB];
    __shared__ int pref[RB];
    __shared__ int cur[RB];
    __shared__ int dbin[DBINS];
    __shared__ int dcur[DBINS];
    __shared__ int nodeOrder[RB];

    const int tid = threadIdx.x;
    const int b = blockIdx.x;
    const size_t s0 = (size_t)b * CAP;
    const int ecount = min(gcnt[b], LDSCAP);

    if (tid < RB) cnt[tid] = 0;
    if (tid < DBINS) dbin[tid] = 0;
    __syncthreads();

    for (int i = tid; i < ecount; i += 512) {
        const int d = ((u32)edata[s0 + i] >> 20) & (RB - 1);
        atomicAdd(&cnt[d], 1);
    }
    __syncthreads();
    if (tid < RB) pref[tid] = cnt[tid];
    __syncthreads();
    for (int o = 1; o < RB; o <<= 1) {
        int v = 0;
        if (tid < RB && tid >= o) v = pref[tid - o];
        __syncthreads();
        if (tid < RB) pref[tid] += v;
        __syncthreads();
    }
    if (tid < RB) {
        cur[tid] = pref[tid] - cnt[tid];
        atomicAdd(&dbin[min(cnt[tid], DBINS - 1)], 1);
    }
    __syncthreads();
    if (tid < DBINS) dcur[tid] = dbin[tid];
    __syncthreads();
    for (int o = 1; o < DBINS; o <<= 1) {
        int v = 0;
        if (tid < DBINS && tid >= o) v = dcur[tid - o];
        __syncthreads();
        if (tid < DBINS) dcur[tid] += v;
        __syncthreads();
    }
    if (tid < DBINS) dcur[tid] -= dbin[tid];
    __syncthreads();
    if (tid < RB) {
        const int r = atomicAdd(&dcur[min(cnt[tid], DBINS - 1)], 1);
        nodeOrder[r] = tid;
    }
    __syncthreads();
    for (int i = tid; i < ecount; i += 512) {
        const u64 ed = edata[s0 + i];
        const int d = ((u32)ed >> 20) & (RB - 1);
        const int p = atomicAdd(&cur[d], 1);
        esh[p] = ed;
    }
    __syncthreads();

    if (tid >= 256) return;
    const int g = tid >> 1;
    const int l = tid & 1;
    const int ln = nodeOrder[g];
    const int gn = b * RB + ln;
    const int end = pref[ln];
    int i = end - cnt[ln];

    float acc[8];
    {
        const float4 ba = *(const float4*)(b2 + 8 * l);
        const float4 bb = *(const float4*)(b2 + 8 * l + 4);
        acc[0] = ba.x; acc[1] = ba.y; acc[2] = ba.z; acc[3] = ba.w;
        acc[4] = bb.x; acc[5] = bb.y; acc[6] = bb.z; acc[7] = bb.w;
    }
    for (; i + 4 <= end; i += 4) {
        u64 e[4];
        uint4 v[4];
        #pragma unroll
        for (int j = 0; j < 4; ++j) e[j] = esh[i + j];
        #pragma unroll
        for (int j = 0; j < 4; ++j)
            v[j] = *(const uint4*)(h2b + (size_t)((u32)e[j] & 0xFFFFF) * 8 + l * 4);
        #pragma unroll
        for (int j = 0; j < 4; ++j) {
            const float w = __uint_as_float((u32)(e[j] >> 32));
            acc[0] += __uint_as_float(v[j].x << 16) * w;
            acc[1] += __uint_as_float(v[j].x & 0xFFFF0000u) * w;
            acc[2] += __uint_as_float(v[j].y << 16) * w;
            acc[3] += __uint_as_float(v[j].y & 0xFFFF0000u) * w;
            acc[4] += __uint_as_float(v[j].z << 16) * w;
            acc[5] += __uint_as_float(v[j].z & 0xFFFF0000u) * w;
            acc[6] += __uint_as_float(v[j].w << 16) * w;
            acc[7] += __uint_as_float(v[j].w & 0xFFFF0000u) * w;
        }
    }
    for (; i < end; ++i) {
        const u64 e0 = esh[i];
        const float w0 = __uint_as_float((u32)(e0 >> 32));
        const uint4 v0 = *(const uint4*)(h2b + (size_t)((u32)e0 & 0xFFFFF) * 8 + l * 4);
        acc[0] += __uint_as_float(v0.x << 16) * w0;
        acc[1] += __uint_as_float(v0.x & 0xFFFF0000u) * w0;
        acc[2] += __uint_as_float(v0.y << 16) * w0;
        acc[3] += __uint_as_float(v0.y & 0xFFFF0000u) * w0;
        acc[4] += __uint_as_float(v0.z << 16) * w0;
        acc[5] += __uint_as_float(v0.z & 0xFFFF0000u) * w0;
        acc[6] += __uint_as_float(v0.w << 16) * w0;
        acc[7] += __uint_as_float(v0.w & 0xFFFF0000u) * w0;
    }
    if (gn < N) {
        float* p = out + (size_t)gn * F_OUT + 8 * l;
        *(float4*)(p + 0) = make_float4(acc[0], acc[1], acc[2], acc[3]);
        *(float4*)(p + 4) = make_float4(acc[4], acc[5], acc[6], acc[7]);
    }
}

extern "C" void kernel_launch(void* const* d_in, const int* in_sizes, int n_in,
                              void* d_out, int out_size, void* d_ws, size_t ws_size,
                              hipStream_t stream) {
    const float* x   = (const float*)d_in[0];
    const int*   src = (const int*)d_in[1];
    const int*   dst = (const int*)d_in[2];
    const float* ew  = (const float*)d_in[3];
    const float* W1  = (const float*)d_in[4];
    const float* b1  = (const float*)d_in[5];
    const float* W2  = (const float*)d_in[6];
    const float* b2  = (const float*)d_in[7];
    float* out = (float*)d_out;

    const int N = in_sizes[0] / F_IN;            // 100000
    const int E = in_sizes[1];                   // 1600000
    const int nbuck = (N + RB - 1) >> RB_SHIFT;  // 782

    char* base = (char*)d_ws;
    auto align256 = [](size_t v) { return (v + 255) & ~(size_t)255; };
    size_t oH1  = 0;
    size_t oED1 = align256(oH1  + (size_t)N * 32 * 4);       // h1 sliced bf16 12.8MB
    size_t oH2B = align256(oED1 + (size_t)nbuck * CAP * 8);  // edata1 19.2MB
    size_t oCUR = align256(oH2B + (size_t)N * 8 * 4);        // h2b bf16 3.2MB
    (void)ws_size;

    u32*   h1s    = (u32*)(base + oH1);
    u64*   edata1 = (u64*)(base + oED1);
    u32*   h2b    = (u32*)(base + oH2B);
    int*   gcur   = (int*)(base + oCUR);

    // ---- preprocessing: CAP-strided bucket fill (counts end up in gcur)
    hipMemsetAsync(gcur, 0, (size_t)nbuck * 4, stream);
    fill_kernel<<<128, 1024, 0, stream>>>(src, dst, ew, gcur, edata1, E, nbuck);

    // ---- layer 1 transform (MFMA bf16, feature-sliced output)
    gemm1_kernel<<<(N + 63) / 64, 256, 0, stream>>>(x, W1, h1s, N);
    // ---- layer-1 aggregate + relu + W2 (4 L2-resident plane passes) -> h2b
    aggL1_kernel<<<nbuck, 1024, 0, stream>>>(h1s, edata1, gcur, b1, W2, h2b, N);
    // ---- layer-2 aggregate + bias (in-LDS sort, 2-lane uint4 gathers)
    aggL2_kernel<<<nbuck, 512, 0, stream>>>(h2b, edata1, gcur, b2, out, N);
}

// Round 15
// 112.141 us; speedup vs baseline: 1.2420x; 1.2420x over previous
//
#include <hip/hip_runtime.h>

#define F_IN 128
#define F_H 64
#define F_OUT 16
#define RB 128           // nodes per bucket
#define RB_SHIFT 7       // bucket = dst >> 7
#define DBINS 64         // degree bins for bucket-local degree ranking
#define CAP 3072         // global bucket capacity (mean 2047, sigma 45)
#define LDSCAP 2816      // LDS sorted-edge capacity (mean + 17 sigma)
#define XSTR 136         // bf16 LDS row stride for gemm1 (16B-aligned b128)

typedef unsigned long long u64;
typedef unsigned int u32;
typedef unsigned short u16;
typedef __attribute__((ext_vector_type(8))) short short8;
typedef __attribute__((ext_vector_type(4))) float floatx4;

__device__ __forceinline__ u32 pack2bf16(float a, float b) {
    u32 ua = (__float_as_uint(a) + 0x8000u) >> 16;
    u32 ub = (__float_as_uint(b) + 0x8000u) & 0xFFFF0000u;
    return ua | ub;
}
__device__ __forceinline__ u16 bf16r(float a) {
    return (u16)((__float_as_uint(a) + 0x8000u) >> 16);
}

// ---------------------------------------------------------------------------
// GEMM1 (MFMA bf16): h1b[N,64](bf16 u32-pair rows) = x[N,128] @ W1[128,64]
// (R13 version, row-major h1b restored)
// ---------------------------------------------------------------------------
__global__ __launch_bounds__(256) void gemm1_kernel(
    const float* __restrict__ x, const float* __restrict__ W,
    u32* __restrict__ h1b, int N) {
    __shared__ u16 sh[2 * 64 * XSTR];    // 34.8 KB: xls | w1t; reused as f32 stage
    u16* xls = sh;
    u16* w1t = sh + 64 * XSTR;
    float* stage = (float*)sh;

    const int tid = threadIdx.x;
    const int n0 = blockIdx.x * 64;

    {   // load x tile -> bf16 LDS
        const int c4 = (tid & 31) * 4;
        const int r0 = tid >> 5;
        #pragma unroll
        for (int r = 0; r < 8; ++r) {
            const int row = r0 + r * 8;
            int n = n0 + row;
            if (n >= N) n = N - 1;
            const float4 v = *(const float4*)(x + (size_t)n * F_IN + c4);
            u16* p = &xls[row * XSTR + c4];
            p[0] = bf16r(v.x); p[1] = bf16r(v.y);
            p[2] = bf16r(v.z); p[3] = bf16r(v.w);
        }
    }
    {   // load W1 transposed -> bf16 LDS: w1t[col][k]
        const int k0 = tid >> 4;
        const int c4 = (tid & 15) * 4;
        #pragma unroll
        for (int r = 0; r < 8; ++r) {
            const int k = k0 + r * 16;
            const float4 v = *(const float4*)(W + (size_t)k * F_H + c4);
            w1t[(c4 + 0) * XSTR + k] = bf16r(v.x);
            w1t[(c4 + 1) * XSTR + k] = bf16r(v.y);
            w1t[(c4 + 2) * XSTR + k] = bf16r(v.z);
            w1t[(c4 + 3) * XSTR + k] = bf16r(v.w);
        }
    }
    __syncthreads();

    const int wv = tid >> 6;
    const int l = tid & 63;
    const int lr = l & 15;
    const int lk = (l >> 4) * 8;

    floatx4 acc[4] = {{0.f, 0.f, 0.f, 0.f}, {0.f, 0.f, 0.f, 0.f},
                      {0.f, 0.f, 0.f, 0.f}, {0.f, 0.f, 0.f, 0.f}};
    #pragma unroll
    for (int ks = 0; ks < 4; ++ks) {
        const short8 a = *(const short8*)&xls[(wv * 16 + lr) * XSTR + ks * 32 + lk];
        #pragma unroll
        for (int c = 0; c < 4; ++c) {
            const short8 bfr = *(const short8*)&w1t[(c * 16 + lr) * XSTR + ks * 32 + lk];
            acc[c] = __builtin_amdgcn_mfma_f32_16x16x32_bf16(a, bfr, acc[c], 0, 0, 0);
        }
    }
    __syncthreads();

    // C layout (verified): col = lane&15, row = (lane>>4)*4 + reg
    #pragma unroll
    for (int c = 0; c < 4; ++c) {
        #pragma unroll
        for (int r = 0; r < 4; ++r) {
            const int row = wv * 16 + (l >> 4) * 4 + r;
            stage[row * 65 + c * 16 + lr] = acc[c][r];
        }
    }
    __syncthreads();

    #pragma unroll
    for (int t = 0; t < 8; ++t) {
        const int idx = t * 256 + tid;
        const int row = idx >> 5, j = idx & 31;
        const int n = n0 + row;
        if (n < N) {
            const float f0 = stage[row * 65 + 2 * j];
            const float f1 = stage[row * 65 + 2 * j + 1];
            h1b[(size_t)n * 32 + j] = pack2bf16(f0, f1);
        }
    }
}

// ---------------------------------------------------------------------------
// fill: block-local counting sort into CAP-strided bucket-grouped edata1
// entry: [63:32]=weight f32 bits, [26:20]=dst&127, [19:0]=src
// ---------------------------------------------------------------------------
__global__ __launch_bounds__(1024) void fill_kernel(
    const int* __restrict__ src, const int* __restrict__ dst,
    const float* __restrict__ ew, int* __restrict__ gcur,
    u64* __restrict__ edata, int E, int nbuck) {
    __shared__ int cnt[800];
    __shared__ int base[800];
    int chunk = (E + gridDim.x - 1) / gridDim.x;
    chunk = (chunk + 3) & ~3;
    const int e0 = blockIdx.x * chunk;
    const int e1 = min(e0 + chunk, E);

    for (int i = threadIdx.x; i < nbuck; i += 1024) cnt[i] = 0;
    __syncthreads();

    int e = e0 + threadIdx.x * 4;
    for (; e + 3 < e1; e += 4096) {
        const int4 d4 = *(const int4*)(dst + e);
        atomicAdd(&cnt[d4.x >> RB_SHIFT], 1);
        atomicAdd(&cnt[d4.y >> RB_SHIFT], 1);
        atomicAdd(&cnt[d4.z >> RB_SHIFT], 1);
        atomicAdd(&cnt[d4.w >> RB_SHIFT], 1);
    }
    for (; e < e1; ++e) atomicAdd(&cnt[dst[e] >> RB_SHIFT], 1);
    __syncthreads();

    for (int i = threadIdx.x; i < nbuck; i += 1024) {
        const int c = cnt[i];
        base[i] = i * CAP + (c ? atomicAdd(&gcur[i], c) : 0);
        cnt[i] = 0;
    }
    __syncthreads();

    e = e0 + threadIdx.x * 4;
    for (; e + 3 < e1; e += 4096) {
        const int4 d4 = *(const int4*)(dst + e);
        const int4 s4 = *(const int4*)(src + e);
        const float4 w4 = *(const float4*)(ew + e);
        {
            const int b = d4.x >> RB_SHIFT;
            const int p = atomicAdd(&cnt[b], 1);
            edata[(size_t)base[b] + p] = ((u64)__float_as_uint(w4.x) << 32) |
                (u32)s4.x | ((u32)(d4.x & (RB - 1)) << 20);
        }
        {
            const int b = d4.y >> RB_SHIFT;
            const int p = atomicAdd(&cnt[b], 1);
            edata[(size_t)base[b] + p] = ((u64)__float_as_uint(w4.y) << 32) |
                (u32)s4.y | ((u32)(d4.y & (RB - 1)) << 20);
        }
        {
            const int b = d4.z >> RB_SHIFT;
            const int p = atomicAdd(&cnt[b], 1);
            edata[(size_t)base[b] + p] = ((u64)__float_as_uint(w4.z) << 32) |
                (u32)s4.z | ((u32)(d4.z & (RB - 1)) << 20);
        }
        {
            const int b = d4.w >> RB_SHIFT;
            const int p = atomicAdd(&cnt[b], 1);
            edata[(size_t)base[b] + p] = ((u64)__float_as_uint(w4.w) << 32) |
                (u32)s4.w | ((u32)(d4.w & (RB - 1)) << 20);
        }
    }
    for (; e < e1; ++e) {
        const int d = dst[e];
        const int b = d >> RB_SHIFT;
        const int p = atomicAdd(&cnt[b], 1);
        edata[(size_t)base[b] + p] = ((u64)__float_as_uint(ew[e]) << 32) |
            (u32)src[e] | ((u32)(d & (RB - 1)) << 20);
    }
}

// ---------------------------------------------------------------------------
// aggL1: one 1024-thread block per bucket (R13 aggregation, unchanged), plus:
//  - writes node-sorted edges back IN PLACE (coalesced, block-owned slice)
//  - writes rowbeg/rowend/perm so aggL2 can skip the sort entirely
// ---------------------------------------------------------------------------
__global__ __launch_bounds__(1024) void aggL1_kernel(
    const u32* __restrict__ h1b, u64* __restrict__ edata,
    const int* __restrict__ gcnt, const float* __restrict__ b1,
    const float* __restrict__ W2, u32* __restrict__ h2b,
    int* __restrict__ rowbeg, int* __restrict__ rowend,
    int* __restrict__ perm, int N) {
    __shared__ u64 esh[LDSCAP];          // sorted edges; reused as bf16 staging
    __shared__ float w2s[64 * 16];
    __shared__ int cnt[RB];
    __shared__ int pref[RB];
    __shared__ int cur[RB];
    __shared__ int dbin[DBINS];
    __shared__ int dcur[DBINS];
    __shared__ int nodeOrder[RB];

    const int tid = threadIdx.x;
    const int b = blockIdx.x;
    const size_t s0 = (size_t)b * CAP;
    const int ecount = min(gcnt[b], LDSCAP);

    w2s[tid] = W2[tid];
    if (tid < RB) cnt[tid] = 0;
    if (tid < DBINS) dbin[tid] = 0;
    __syncthreads();

    for (int i = tid; i < ecount; i += 1024) {
        const int d = ((u32)edata[s0 + i] >> 20) & (RB - 1);
        atomicAdd(&cnt[d], 1);
    }
    __syncthreads();
    if (tid < RB) pref[tid] = cnt[tid];
    __syncthreads();
    for (int o = 1; o < RB; o <<= 1) {
        int v = 0;
        if (tid < RB && tid >= o) v = pref[tid - o];
        __syncthreads();
        if (tid < RB) pref[tid] += v;
        __syncthreads();
    }
    if (tid < RB) {
        cur[tid] = pref[tid] - cnt[tid];
        const int gn = b * RB + tid;
        rowbeg[gn] = (int)s0 + pref[tid] - cnt[tid];
        rowend[gn] = (int)s0 + pref[tid];
        atomicAdd(&dbin[min(cnt[tid], DBINS - 1)], 1);
    }
    __syncthreads();
    if (tid < DBINS) dcur[tid] = dbin[tid];
    __syncthreads();
    for (int o = 1; o < DBINS; o <<= 1) {
        int v = 0;
        if (tid < DBINS && tid >= o) v = dcur[tid - o];
        __syncthreads();
        if (tid < DBINS) dcur[tid] += v;
        __syncthreads();
    }
    if (tid < DBINS) dcur[tid] -= dbin[tid];
    __syncthreads();
    if (tid < RB) {
        const int r = atomicAdd(&dcur[min(cnt[tid], DBINS - 1)], 1);
        nodeOrder[r] = tid;
        perm[b * RB + r] = b * RB + tid;
    }
    for (int i = tid; i < ecount; i += 1024) {
        const u64 ed = edata[s0 + i];
        const int d = ((u32)ed >> 20) & (RB - 1);
        const int p = atomicAdd(&cur[d], 1);
        esh[p] = ed;
    }
    __syncthreads();

    // persist sorted edges (coalesced; block owns this slice)
    for (int i = tid; i < ecount; i += 1024) edata[s0 + i] = esh[i];

    // ---- aggregation (R13, unchanged) ----
    const int g = tid >> 3;
    const int l = tid & 7;
    const int ln = nodeOrder[g];
    const int end = pref[ln];
    int i = end - cnt[ln];

    float acc[8];
    {
        const float4 ba = *(const float4*)(b1 + 8 * l);
        const float4 bb = *(const float4*)(b1 + 8 * l + 4);
        acc[0] = ba.x; acc[1] = ba.y; acc[2] = ba.z; acc[3] = ba.w;
        acc[4] = bb.x; acc[5] = bb.y; acc[6] = bb.z; acc[7] = bb.w;
    }
    for (; i + 4 <= end; i += 4) {
        u64 e[4];
        uint4 v[4];
        #pragma unroll
        for (int j = 0; j < 4; ++j) e[j] = esh[i + j];
        #pragma unroll
        for (int j = 0; j < 4; ++j)
            v[j] = *(const uint4*)(h1b + (size_t)((u32)e[j] & 0xFFFFF) * 32 + l * 4);
        #pragma unroll
        for (int j = 0; j < 4; ++j) {
            const float w = __uint_as_float((u32)(e[j] >> 32));
            acc[0] += __uint_as_float(v[j].x << 16) * w;
            acc[1] += __uint_as_float(v[j].x & 0xFFFF0000u) * w;
            acc[2] += __uint_as_float(v[j].y << 16) * w;
            acc[3] += __uint_as_float(v[j].y & 0xFFFF0000u) * w;
            acc[4] += __uint_as_float(v[j].z << 16) * w;
            acc[5] += __uint_as_float(v[j].z & 0xFFFF0000u) * w;
            acc[6] += __uint_as_float(v[j].w << 16) * w;
            acc[7] += __uint_as_float(v[j].w & 0xFFFF0000u) * w;
        }
    }
    for (; i < end; ++i) {
        const u64 e0 = esh[i];
        const float w0 = __uint_as_float((u32)(e0 >> 32));
        const uint4 v0 = *(const uint4*)(h1b + (size_t)((u32)e0 & 0xFFFFF) * 32 + l * 4);
        acc[0] += __uint_as_float(v0.x << 16) * w0;
        acc[1] += __uint_as_float(v0.x & 0xFFFF0000u) * w0;
        acc[2] += __uint_as_float(v0.y << 16) * w0;
        acc[3] += __uint_as_float(v0.y & 0xFFFF0000u) * w0;
        acc[4] += __uint_as_float(v0.z << 16) * w0;
        acc[5] += __uint_as_float(v0.z & 0xFFFF0000u) * w0;
        acc[6] += __uint_as_float(v0.w << 16) * w0;
        acc[7] += __uint_as_float(v0.w & 0xFFFF0000u) * w0;
    }

    u32 pk[4];
    #pragma unroll
    for (int j = 0; j < 4; ++j)
        pk[j] = pack2bf16(fmaxf(acc[2 * j], 0.f), fmaxf(acc[2 * j + 1], 0.f));

    __syncthreads();                     // all esh reads (agg + persist) done
    u32* stg = (u32*)esh;
    #pragma unroll
    for (int j = 0; j < 4; ++j) stg[g * 32 + l * 4 + j] = pk[j];
    __syncthreads();

    const int s = tid >> 3;
    const int c = tid & 7;
    float o0 = 0.f, o1 = 0.f;
    #pragma unroll 8
    for (int w = 0; w < 32; ++w) {
        const u32 pw = stg[s * 32 + w];
        const float f0 = __uint_as_float(pw << 16);
        const float f1 = __uint_as_float(pw & 0xFFFF0000u);
        o0 += f0 * w2s[(2 * w) * 16 + 2 * c] + f1 * w2s[(2 * w + 1) * 16 + 2 * c];
        o1 += f0 * w2s[(2 * w) * 16 + 2 * c + 1] + f1 * w2s[(2 * w + 1) * 16 + 2 * c + 1];
    }
    const int gn = b * RB + nodeOrder[s];
    if (gn < N) h2b[(size_t)gn * 8 + c] = pack2bf16(o0, o1);
}

// ---------------------------------------------------------------------------
// aggL2: flat 256-thread kernel, 2 lanes/node in degree-ranked perm order.
// Reads node-sorted runs persisted by aggL1 — no LDS, no sort, no scans.
// ---------------------------------------------------------------------------
__global__ __launch_bounds__(256) void aggL2_kernel(
    const u32* __restrict__ h2b, const u64* __restrict__ edata,
    const int* __restrict__ rowbeg, const int* __restrict__ rowend,
    const int* __restrict__ perm, const float* __restrict__ b2,
    float* __restrict__ out, int NP, int N) {
    const int tid = threadIdx.x;
    const int idx = (blockIdx.x * 256 + tid) >> 1;
    if (idx >= NP) return;
    const int n = perm[idx];
    const int l = tid & 1;               // feats 8l .. 8l+7 (16B half)

    int i = rowbeg[n];
    const int end = rowend[n];

    float acc[8];
    {
        const float4 ba = *(const float4*)(b2 + 8 * l);
        const float4 bb = *(const float4*)(b2 + 8 * l + 4);
        acc[0] = ba.x; acc[1] = ba.y; acc[2] = ba.z; acc[3] = ba.w;
        acc[4] = bb.x; acc[5] = bb.y; acc[6] = bb.z; acc[7] = bb.w;
    }
    for (; i + 4 <= end; i += 4) {
        u64 e[4];
        uint4 v[4];
        #pragma unroll
        for (int j = 0; j < 4; ++j) e[j] = edata[i + j];
        #pragma unroll
        for (int j = 0; j < 4; ++j)
            v[j] = *(const uint4*)(h2b + (size_t)((u32)e[j] & 0xFFFFF) * 8 + l * 4);
        #pragma unroll
        for (int j = 0; j < 4; ++j) {
            const float w = __uint_as_float((u32)(e[j] >> 32));
            acc[0] += __uint_as_float(v[j].x << 16) * w;
            acc[1] += __uint_as_float(v[j].x & 0xFFFF0000u) * w;
            acc[2] += __uint_as_float(v[j].y << 16) * w;
            acc[3] += __uint_as_float(v[j].y & 0xFFFF0000u) * w;
            acc[4] += __uint_as_float(v[j].z << 16) * w;
            acc[5] += __uint_as_float(v[j].z & 0xFFFF0000u) * w;
            acc[6] += __uint_as_float(v[j].w << 16) * w;
            acc[7] += __uint_as_float(v[j].w & 0xFFFF0000u) * w;
        }
    }
    for (; i < end; ++i) {
        const u64 e0 = edata[i];
        const float w0 = __uint_as_float((u32)(e0 >> 32));
        const uint4 v0 = *(const uint4*)(h2b + (size_t)((u32)e0 & 0xFFFFF) * 8 + l * 4);
        acc[0] += __uint_as_float(v0.x << 16) * w0;
        acc[1] += __uint_as_float(v0.x & 0xFFFF0000u) * w0;
        acc[2] += __uint_as_float(v0.y << 16) * w0;
        acc[3] += __uint_as_float(v0.y & 0xFFFF0000u) * w0;
        acc[4] += __uint_as_float(v0.z << 16) * w0;
        acc[5] += __uint_as_float(v0.z & 0xFFFF0000u) * w0;
        acc[6] += __uint_as_float(v0.w << 16) * w0;
        acc[7] += __uint_as_float(v0.w & 0xFFFF0000u) * w0;
    }
    if (n < N) {
        float* p = out + (size_t)n * F_OUT + 8 * l;
        *(float4*)(p + 0) = make_float4(acc[0], acc[1], acc[2], acc[3]);
        *(float4*)(p + 4) = make_float4(acc[4], acc[5], acc[6], acc[7]);
    }
}

extern "C" void kernel_launch(void* const* d_in, const int* in_sizes, int n_in,
                              void* d_out, int out_size, void* d_ws, size_t ws_size,
                              hipStream_t stream) {
    const float* x   = (const float*)d_in[0];
    const int*   src = (const int*)d_in[1];
    const int*   dst = (const int*)d_in[2];
    const float* ew  = (const float*)d_in[3];
    const float* W1  = (const float*)d_in[4];
    const float* b1  = (const float*)d_in[5];
    const float* W2  = (const float*)d_in[6];
    const float* b2  = (const float*)d_in[7];
    float* out = (float*)d_out;

    const int N = in_sizes[0] / F_IN;            // 100000
    const int E = in_sizes[1];                   // 1600000
    const int nbuck = (N + RB - 1) >> RB_SHIFT;  // 782
    const int NP = nbuck * RB;                   // 100096

    char* base = (char*)d_ws;
    auto align256 = [](size_t v) { return (v + 255) & ~(size_t)255; };
    size_t oH1   = 0;
    size_t oED1  = align256(oH1   + (size_t)N * 32 * 4);      // h1b bf16 12.8MB
    size_t oH2B  = align256(oED1  + (size_t)nbuck * CAP * 8); // edata1 19.2MB
    size_t oCUR  = align256(oH2B  + (size_t)N * 8 * 4);       // h2b bf16 3.2MB
    size_t oRB_  = align256(oCUR  + (size_t)nbuck * 4);
    size_t oRE_  = align256(oRB_  + (size_t)NP * 4);
    size_t oPERM = align256(oRE_  + (size_t)NP * 4);
    (void)ws_size;

    u32*   h1b    = (u32*)(base + oH1);
    u64*   edata1 = (u64*)(base + oED1);
    u32*   h2b    = (u32*)(base + oH2B);
    int*   gcur   = (int*)(base + oCUR);
    int*   rowbeg = (int*)(base + oRB_);
    int*   rowend = (int*)(base + oRE_);
    int*   perm   = (int*)(base + oPERM);

    // ---- preprocessing: CAP-strided bucket fill (counts end up in gcur)
    hipMemsetAsync(gcur, 0, (size_t)nbuck * 4, stream);
    fill_kernel<<<128, 1024, 0, stream>>>(src, dst, ew, gcur, edata1, E, nbuck);

    // ---- layer 1 transform (MFMA bf16)
    gemm1_kernel<<<(N + 63) / 64, 256, 0, stream>>>(x, W1, h1b, N);
    // ---- layer-1 aggregate + relu + W2; persists sorted edges + run bounds
    aggL1_kernel<<<nbuck, 1024, 0, stream>>>(h1b, edata1, gcur, b1, W2, h2b,
                                             rowbeg, rowend, perm, N);
    // ---- layer-2 aggregate + bias (flat, no sort)
    aggL2_kernel<<<(NP * 2 + 255) / 256, 256, 0, stream>>>(
        h2b, edata1, rowbeg, rowend, perm, b2, out, NP, N);
}

// Round 16
// 111.337 us; speedup vs baseline: 1.2510x; 1.0072x over previous
//
#include <hip/hip_runtime.h>

#define F_IN 128
#define F_H 64
#define F_OUT 16
#define RB 128           // nodes per bucket
#define RB_SHIFT 7       // bucket = dst >> 7
#define DBINS 64         // degree bins for bucket-local degree ranking
#define CAP 3072         // global bucket capacity (mean 2047, sigma 45)
#define LDSCAP 2816      // LDS sorted-edge capacity (mean + 17 sigma)
#define XSTR 136         // bf16 LDS row stride for gemm1 (16B-aligned b128)

typedef unsigned long long u64;
typedef unsigned int u32;
typedef unsigned short u16;
typedef __attribute__((ext_vector_type(8))) short short8;
typedef __attribute__((ext_vector_type(4))) float floatx4;

__device__ __forceinline__ u32 pack2bf16(float a, float b) {
    u32 ua = (__float_as_uint(a) + 0x8000u) >> 16;
    u32 ub = (__float_as_uint(b) + 0x8000u) & 0xFFFF0000u;
    return ua | ub;
}
__device__ __forceinline__ u16 bf16r(float a) {
    return (u16)((__float_as_uint(a) + 0x8000u) >> 16);
}

// ---------------------------------------------------------------------------
// GEMM1 (MFMA bf16): h1b[N,64](bf16 u32-pair rows) = x[N,128] @ W1[128,64]
// (R13 version)
// ---------------------------------------------------------------------------
__global__ __launch_bounds__(256) void gemm1_kernel(
    const float* __restrict__ x, const float* __restrict__ W,
    u32* __restrict__ h1b, int N) {
    __shared__ u16 sh[2 * 64 * XSTR];    // 34.8 KB: xls | w1t; reused as f32 stage
    u16* xls = sh;
    u16* w1t = sh + 64 * XSTR;
    float* stage = (float*)sh;

    const int tid = threadIdx.x;
    const int n0 = blockIdx.x * 64;

    {   // load x tile -> bf16 LDS
        const int c4 = (tid & 31) * 4;
        const int r0 = tid >> 5;
        #pragma unroll
        for (int r = 0; r < 8; ++r) {
            const int row = r0 + r * 8;
            int n = n0 + row;
            if (n >= N) n = N - 1;
            const float4 v = *(const float4*)(x + (size_t)n * F_IN + c4);
            u16* p = &xls[row * XSTR + c4];
            p[0] = bf16r(v.x); p[1] = bf16r(v.y);
            p[2] = bf16r(v.z); p[3] = bf16r(v.w);
        }
    }
    {   // load W1 transposed -> bf16 LDS: w1t[col][k]
        const int k0 = tid >> 4;
        const int c4 = (tid & 15) * 4;
        #pragma unroll
        for (int r = 0; r < 8; ++r) {
            const int k = k0 + r * 16;
            const float4 v = *(const float4*)(W + (size_t)k * F_H + c4);
            w1t[(c4 + 0) * XSTR + k] = bf16r(v.x);
            w1t[(c4 + 1) * XSTR + k] = bf16r(v.y);
            w1t[(c4 + 2) * XSTR + k] = bf16r(v.z);
            w1t[(c4 + 3) * XSTR + k] = bf16r(v.w);
        }
    }
    __syncthreads();

    const int wv = tid >> 6;
    const int l = tid & 63;
    const int lr = l & 15;
    const int lk = (l >> 4) * 8;

    floatx4 acc[4] = {{0.f, 0.f, 0.f, 0.f}, {0.f, 0.f, 0.f, 0.f},
                      {0.f, 0.f, 0.f, 0.f}, {0.f, 0.f, 0.f, 0.f}};
    #pragma unroll
    for (int ks = 0; ks < 4; ++ks) {
        const short8 a = *(const short8*)&xls[(wv * 16 + lr) * XSTR + ks * 32 + lk];
        #pragma unroll
        for (int c = 0; c < 4; ++c) {
            const short8 bfr = *(const short8*)&w1t[(c * 16 + lr) * XSTR + ks * 32 + lk];
            acc[c] = __builtin_amdgcn_mfma_f32_16x16x32_bf16(a, bfr, acc[c], 0, 0, 0);
        }
    }
    __syncthreads();

    // C layout (verified): col = lane&15, row = (lane>>4)*4 + reg
    #pragma unroll
    for (int c = 0; c < 4; ++c) {
        #pragma unroll
        for (int r = 0; r < 4; ++r) {
            const int row = wv * 16 + (l >> 4) * 4 + r;
            stage[row * 65 + c * 16 + lr] = acc[c][r];
        }
    }
    __syncthreads();

    #pragma unroll
    for (int t = 0; t < 8; ++t) {
        const int idx = t * 256 + tid;
        const int row = idx >> 5, j = idx & 31;
        const int n = n0 + row;
        if (n < N) {
            const float f0 = stage[row * 65 + 2 * j];
            const float f1 = stage[row * 65 + 2 * j + 1];
            h1b[(size_t)n * 32 + j] = pack2bf16(f0, f1);
        }
    }
}

// ---------------------------------------------------------------------------
// fill: block-local counting sort into CAP-strided bucket-grouped edata1
// entry: [63:32]=weight f32 bits, [26:20]=dst&127, [19:0]=src
// ---------------------------------------------------------------------------
__global__ __launch_bounds__(1024) void fill_kernel(
    const int* __restrict__ src, const int* __restrict__ dst,
    const float* __restrict__ ew, int* __restrict__ gcur,
    u64* __restrict__ edata, int E, int nbuck) {
    __shared__ int cnt[800];
    __shared__ int base[800];
    int chunk = (E + gridDim.x - 1) / gridDim.x;
    chunk = (chunk + 3) & ~3;
    const int e0 = blockIdx.x * chunk;
    const int e1 = min(e0 + chunk, E);

    for (int i = threadIdx.x; i < nbuck; i += 1024) cnt[i] = 0;
    __syncthreads();

    int e = e0 + threadIdx.x * 4;
    for (; e + 3 < e1; e += 4096) {
        const int4 d4 = *(const int4*)(dst + e);
        atomicAdd(&cnt[d4.x >> RB_SHIFT], 1);
        atomicAdd(&cnt[d4.y >> RB_SHIFT], 1);
        atomicAdd(&cnt[d4.z >> RB_SHIFT], 1);
        atomicAdd(&cnt[d4.w >> RB_SHIFT], 1);
    }
    for (; e < e1; ++e) atomicAdd(&cnt[dst[e] >> RB_SHIFT], 1);
    __syncthreads();

    for (int i = threadIdx.x; i < nbuck; i += 1024) {
        const int c = cnt[i];
        base[i] = i * CAP + (c ? atomicAdd(&gcur[i], c) : 0);
        cnt[i] = 0;
    }
    __syncthreads();

    e = e0 + threadIdx.x * 4;
    for (; e + 3 < e1; e += 4096) {
        const int4 d4 = *(const int4*)(dst + e);
        const int4 s4 = *(const int4*)(src + e);
        const float4 w4 = *(const float4*)(ew + e);
        {
            const int b = d4.x >> RB_SHIFT;
            const int p = atomicAdd(&cnt[b], 1);
            edata[(size_t)base[b] + p] = ((u64)__float_as_uint(w4.x) << 32) |
                (u32)s4.x | ((u32)(d4.x & (RB - 1)) << 20);
        }
        {
            const int b = d4.y >> RB_SHIFT;
            const int p = atomicAdd(&cnt[b], 1);
            edata[(size_t)base[b] + p] = ((u64)__float_as_uint(w4.y) << 32) |
                (u32)s4.y | ((u32)(d4.y & (RB - 1)) << 20);
        }
        {
            const int b = d4.z >> RB_SHIFT;
            const int p = atomicAdd(&cnt[b], 1);
            edata[(size_t)base[b] + p] = ((u64)__float_as_uint(w4.z) << 32) |
                (u32)s4.z | ((u32)(d4.z & (RB - 1)) << 20);
        }
        {
            const int b = d4.w >> RB_SHIFT;
            const int p = atomicAdd(&cnt[b], 1);
            edata[(size_t)base[b] + p] = ((u64)__float_as_uint(w4.w) << 32) |
                (u32)s4.w | ((u32)(d4.w & (RB - 1)) << 20);
        }
    }
    for (; e < e1; ++e) {
        const int d = dst[e];
        const int b = d >> RB_SHIFT;
        const int p = atomicAdd(&cnt[b], 1);
        edata[(size_t)base[b] + p] = ((u64)__float_as_uint(ew[e]) << 32) |
            (u32)src[e] | ((u32)(d & (RB - 1)) << 20);
    }
}

// ---------------------------------------------------------------------------
// aggL1: one 1024-thread block per bucket.
//  1) counting-sort edges by key=(srcSlice<<7)|dstLocal into LDS (512 keys);
//     srcSlice = (src>>13)&3 -> 4 slices of ~3.2MB h1 rows (per-XCD L2 fit)
//  2) degree-rank nodes by TOTAL degree
//  3) 128 groups x 8 lanes; 4 block-synchronized slice passes, register acc
//     carried across passes; uint4 bf16 gathers (full 128B line per edge)
//  4) relu+pack -> stg (reused esh); W2 pass -> h2b bf16
// ---------------------------------------------------------------------------
__global__ __launch_bounds__(1024) void aggL1_kernel(
    const u32* __restrict__ h1b, const u64* __restrict__ edata,
    const int* __restrict__ gcnt, const float* __restrict__ b1,
    const float* __restrict__ W2, u32* __restrict__ h2b, int N) {
    __shared__ u64 esh[LDSCAP];          // 22.5 KB sorted edges; reused as staging
    __shared__ float w2s[64 * 16];       // 4 KB
    __shared__ int cnt[512];             // per (slice,node) counts
    __shared__ int pref[512];            // inclusive prefix
    __shared__ int cur[512];
    __shared__ int dbin[DBINS];
    __shared__ int dcur[DBINS];
    __shared__ int nodeOrder[RB];
    __shared__ int ndeg[RB];

    const int tid = threadIdx.x;
    const int b = blockIdx.x;
    const size_t s0 = (size_t)b * CAP;
    const int ecount = min(gcnt[b], LDSCAP);

    w2s[tid] = W2[tid];
    if (tid < 512) cnt[tid] = 0;
    if (tid < DBINS) dbin[tid] = 0;
    __syncthreads();

    // pass 1: per-(slice,node) counts
    for (int i = tid; i < ecount; i += 1024) {
        const u32 lo = (u32)edata[s0 + i];
        const int key = (((lo & 0xFFFFF) >> 13) & 3) * 128 + ((lo >> 20) & (RB - 1));
        atomicAdd(&cnt[key], 1);
    }
    __syncthreads();
    if (tid < 512) pref[tid] = cnt[tid];
    __syncthreads();
    for (int o = 1; o < 512; o <<= 1) {
        int v = 0;
        if (tid < 512 && tid >= o) v = pref[tid - o];
        __syncthreads();
        if (tid < 512) pref[tid] += v;
        __syncthreads();
    }
    if (tid < 512) cur[tid] = pref[tid] - cnt[tid];
    if (tid < RB) {
        const int nd = cnt[tid] + cnt[128 + tid] + cnt[256 + tid] + cnt[384 + tid];
        ndeg[tid] = nd;
        atomicAdd(&dbin[min(nd, DBINS - 1)], 1);
    }
    __syncthreads();
    if (tid < DBINS) dcur[tid] = dbin[tid];
    __syncthreads();
    for (int o = 1; o < DBINS; o <<= 1) {
        int v = 0;
        if (tid < DBINS && tid >= o) v = dcur[tid - o];
        __syncthreads();
        if (tid < DBINS) dcur[tid] += v;
        __syncthreads();
    }
    if (tid < DBINS) dcur[tid] -= dbin[tid];
    __syncthreads();
    if (tid < RB) {
        const int r = atomicAdd(&dcur[min(ndeg[tid], DBINS - 1)], 1);
        nodeOrder[r] = tid;
    }
    // pass 2: scatter edges into LDS in (slice,node)-sorted order
    for (int i = tid; i < ecount; i += 1024) {
        const u64 ed = edata[s0 + i];
        const u32 lo = (u32)ed;
        const int key = (((lo & 0xFFFFF) >> 13) & 3) * 128 + ((lo >> 20) & (RB - 1));
        const int p = atomicAdd(&cur[key], 1);
        esh[p] = ed;
    }
    __syncthreads();

    // gather: group g (8 lanes) = degree rank g; 4 slice passes, acc carried
    const int g = tid >> 3;
    const int l = tid & 7;
    const int ln = nodeOrder[g];

    float acc[8];
    {
        const float4 ba = *(const float4*)(b1 + 8 * l);
        const float4 bb = *(const float4*)(b1 + 8 * l + 4);
        acc[0] = ba.x; acc[1] = ba.y; acc[2] = ba.z; acc[3] = ba.w;
        acc[4] = bb.x; acc[5] = bb.y; acc[6] = bb.z; acc[7] = bb.w;
    }
    #pragma unroll
    for (int p = 0; p < 4; ++p) {
        const int key = p * 128 + ln;
        const int end = pref[key];
        int i = end - cnt[key];
        for (; i + 4 <= end; i += 4) {
            u64 e[4];
            uint4 v[4];
            #pragma unroll
            for (int j = 0; j < 4; ++j) e[j] = esh[i + j];
            #pragma unroll
            for (int j = 0; j < 4; ++j)
                v[j] = *(const uint4*)(h1b + (size_t)((u32)e[j] & 0xFFFFF) * 32 + l * 4);
            #pragma unroll
            for (int j = 0; j < 4; ++j) {
                const float w = __uint_as_float((u32)(e[j] >> 32));
                acc[0] += __uint_as_float(v[j].x << 16) * w;
                acc[1] += __uint_as_float(v[j].x & 0xFFFF0000u) * w;
                acc[2] += __uint_as_float(v[j].y << 16) * w;
                acc[3] += __uint_as_float(v[j].y & 0xFFFF0000u) * w;
                acc[4] += __uint_as_float(v[j].z << 16) * w;
                acc[5] += __uint_as_float(v[j].z & 0xFFFF0000u) * w;
                acc[6] += __uint_as_float(v[j].w << 16) * w;
                acc[7] += __uint_as_float(v[j].w & 0xFFFF0000u) * w;
            }
        }
        for (; i < end; ++i) {
            const u64 e0 = esh[i];
            const float w0 = __uint_as_float((u32)(e0 >> 32));
            const uint4 v0 = *(const uint4*)(h1b + (size_t)((u32)e0 & 0xFFFFF) * 32 + l * 4);
            acc[0] += __uint_as_float(v0.x << 16) * w0;
            acc[1] += __uint_as_float(v0.x & 0xFFFF0000u) * w0;
            acc[2] += __uint_as_float(v0.y << 16) * w0;
            acc[3] += __uint_as_float(v0.y & 0xFFFF0000u) * w0;
            acc[4] += __uint_as_float(v0.z << 16) * w0;
            acc[5] += __uint_as_float(v0.z & 0xFFFF0000u) * w0;
            acc[6] += __uint_as_float(v0.w << 16) * w0;
            acc[7] += __uint_as_float(v0.w & 0xFFFF0000u) * w0;
        }
        __syncthreads();                 // slice sync: keep block on one slice
    }

    // relu + pack to bf16 (last barrier above also guards esh reuse)
    u32 pk[4];
    #pragma unroll
    for (int j = 0; j < 4; ++j)
        pk[j] = pack2bf16(fmaxf(acc[2 * j], 0.f), fmaxf(acc[2 * j + 1], 0.f));

    u32* stg = (u32*)esh;                // 128 * 32 u32 = 16 KB
    #pragma unroll
    for (int j = 0; j < 4; ++j) stg[g * 32 + l * 4 + j] = pk[j];
    __syncthreads();

    // W2 pass: slot s = tid>>3 (rank), col pair c = tid&7 (cols 2c, 2c+1)
    const int s = tid >> 3;
    const int c = tid & 7;
    float o0 = 0.f, o1 = 0.f;
    #pragma unroll 8
    for (int w = 0; w < 32; ++w) {
        const u32 pw = stg[s * 32 + w];
        const float f0 = __uint_as_float(pw << 16);
        const float f1 = __uint_as_float(pw & 0xFFFF0000u);
        o0 += f0 * w2s[(2 * w) * 16 + 2 * c] + f1 * w2s[(2 * w + 1) * 16 + 2 * c];
        o1 += f0 * w2s[(2 * w) * 16 + 2 * c + 1] + f1 * w2s[(2 * w + 1) * 16 + 2 * c + 1];
    }
    const int gn = b * RB + nodeOrder[s];
    if (gn < N) h2b[(size_t)gn * 8 + c] = pack2bf16(o0, o1);
}

// ---------------------------------------------------------------------------
// aggL2: one 512-thread block per bucket. (R13 version, verbatim)
// ---------------------------------------------------------------------------
__global__ __launch_bounds__(512) void aggL2_kernel(
    const u32* __restrict__ h2b, const u64* __restrict__ edata,
    const int* __restrict__ gcnt, const float* __restrict__ b2,
    float* __restrict__ out, int N) {
    __shared__ u64 esh[LDSCAP];
    __shared__ int cnt[RB];
    __shared__ int pref[RB];
    __shared__ int cur[RB];
    __shared__ int dbin[DBINS];
    __shared__ int dcur[DBINS];
    __shared__ int nodeOrder[RB];

    const int tid = threadIdx.x;
    const int b = blockIdx.x;
    const size_t s0 = (size_t)b * CAP;
    const int ecount = min(gcnt[b], LDSCAP);

    if (tid < RB) cnt[tid] = 0;
    if (tid < DBINS) dbin[tid] = 0;
    __syncthreads();

    for (int i = tid; i < ecount; i += 512) {
        const int d = ((u32)edata[s0 + i] >> 20) & (RB - 1);
        atomicAdd(&cnt[d], 1);
    }
    __syncthreads();
    if (tid < RB) pref[tid] = cnt[tid];
    __syncthreads();
    for (int o = 1; o < RB; o <<= 1) {
        int v = 0;
        if (tid < RB && tid >= o) v = pref[tid - o];
        __syncthreads();
        if (tid < RB) pref[tid] += v;
        __syncthreads();
    }
    if (tid < RB) {
        cur[tid] = pref[tid] - cnt[tid];
        atomicAdd(&dbin[min(cnt[tid], DBINS - 1)], 1);
    }
    __syncthreads();
    if (tid < DBINS) dcur[tid] = dbin[tid];
    __syncthreads();
    for (int o = 1; o < DBINS; o <<= 1) {
        int v = 0;
        if (tid < DBINS && tid >= o) v = dcur[tid - o];
        __syncthreads();
        if (tid < DBINS) dcur[tid] += v;
        __syncthreads();
    }
    if (tid < DBINS) dcur[tid] -= dbin[tid];
    __syncthreads();
    if (tid < RB) {
        const int r = atomicAdd(&dcur[min(cnt[tid], DBINS - 1)], 1);
        nodeOrder[r] = tid;
    }
    __syncthreads();
    for (int i = tid; i < ecount; i += 512) {
        const u64 ed = edata[s0 + i];
        const int d = ((u32)ed >> 20) & (RB - 1);
        const int p = atomicAdd(&cur[d], 1);
        esh[p] = ed;
    }
    __syncthreads();

    if (tid >= 256) return;
    const int g = tid >> 1;
    const int l = tid & 1;
    const int ln = nodeOrder[g];
    const int gn = b * RB + ln;
    const int end = pref[ln];
    int i = end - cnt[ln];

    float acc[8];
    {
        const float4 ba = *(const float4*)(b2 + 8 * l);
        const float4 bb = *(const float4*)(b2 + 8 * l + 4);
        acc[0] = ba.x; acc[1] = ba.y; acc[2] = ba.z; acc[3] = ba.w;
        acc[4] = bb.x; acc[5] = bb.y; acc[6] = bb.z; acc[7] = bb.w;
    }
    for (; i + 4 <= end; i += 4) {
        u64 e[4];
        uint4 v[4];
        #pragma unroll
        for (int j = 0; j < 4; ++j) e[j] = esh[i + j];
        #pragma unroll
        for (int j = 0; j < 4; ++j)
            v[j] = *(const uint4*)(h2b + (size_t)((u32)e[j] & 0xFFFFF) * 8 + l * 4);
        #pragma unroll
        for (int j = 0; j < 4; ++j) {
            const float w = __uint_as_float((u32)(e[j] >> 32));
            acc[0] += __uint_as_float(v[j].x << 16) * w;
            acc[1] += __uint_as_float(v[j].x & 0xFFFF0000u) * w;
            acc[2] += __uint_as_float(v[j].y << 16) * w;
            acc[3] += __uint_as_float(v[j].y & 0xFFFF0000u) * w;
            acc[4] += __uint_as_float(v[j].z << 16) * w;
            acc[5] += __uint_as_float(v[j].z & 0xFFFF0000u) * w;
            acc[6] += __uint_as_float(v[j].w << 16) * w;
            acc[7] += __uint_as_float(v[j].w & 0xFFFF0000u) * w;
        }
    }
    for (; i < end; ++i) {
        const u64 e0 = esh[i];
        const float w0 = __uint_as_float((u32)(e0 >> 32));
        const uint4 v0 = *(const uint4*)(h2b + (size_t)((u32)e0 & 0xFFFFF) * 8 + l * 4);
        acc[0] += __uint_as_float(v0.x << 16) * w0;
        acc[1] += __uint_as_float(v0.x & 0xFFFF0000u) * w0;
        acc[2] += __uint_as_float(v0.y << 16) * w0;
        acc[3] += __uint_as_float(v0.y & 0xFFFF0000u) * w0;
        acc[4] += __uint_as_float(v0.z << 16) * w0;
        acc[5] += __uint_as_float(v0.z & 0xFFFF0000u) * w0;
        acc[6] += __uint_as_float(v0.w << 16) * w0;
        acc[7] += __uint_as_float(v0.w & 0xFFFF0000u) * w0;
    }
    if (gn < N) {
        float* p = out + (size_t)gn * F_OUT + 8 * l;
        *(float4*)(p + 0) = make_float4(acc[0], acc[1], acc[2], acc[3]);
        *(float4*)(p + 4) = make_float4(acc[4], acc[5], acc[6], acc[7]);
    }
}

extern "C" void kernel_launch(void* const* d_in, const int* in_sizes, int n_in,
                              void* d_out, int out_size, void* d_ws, size_t ws_size,
                              hipStream_t stream) {
    const float* x   = (const float*)d_in[0];
    const int*   src = (const int*)d_in[1];
    const int*   dst = (const int*)d_in[2];
    const float* ew  = (const float*)d_in[3];
    const float* W1  = (const float*)d_in[4];
    const float* b1  = (const float*)d_in[5];
    const float* W2  = (const float*)d_in[6];
    const float* b2  = (const float*)d_in[7];
    float* out = (float*)d_out;

    const int N = in_sizes[0] / F_IN;            // 100000
    const int E = in_sizes[1];                   // 1600000
    const int nbuck = (N + RB - 1) >> RB_SHIFT;  // 782

    char* base = (char*)d_ws;
    auto align256 = [](size_t v) { return (v + 255) & ~(size_t)255; };
    size_t oH1  = 0;
    size_t oED1 = align256(oH1  + (size_t)N * 32 * 4);       // h1b bf16 12.8MB
    size_t oH2B = align256(oED1 + (size_t)nbuck * CAP * 8);  // edata1 19.2MB
    size_t oCUR = align256(oH2B + (size_t)N * 8 * 4);        // h2b bf16 3.2MB
    (void)ws_size;

    u32*   h1b    = (u32*)(base + oH1);
    u64*   edata1 = (u64*)(base + oED1);
    u32*   h2b    = (u32*)(base + oH2B);
    int*   gcur   = (int*)(base + oCUR);

    // ---- preprocessing: CAP-strided bucket fill (counts end up in gcur)
    hipMemsetAsync(gcur, 0, (size_t)nbuck * 4, stream);
    fill_kernel<<<128, 1024, 0, stream>>>(src, dst, ew, gcur, edata1, E, nbuck);

    // ---- layer 1 transform (MFMA bf16)
    gemm1_kernel<<<(N + 63) / 64, 256, 0, stream>>>(x, W1, h1b, N);
    // ---- layer-1 aggregate + relu + W2 (slice-sorted, 4 L2 passes) -> h2b
    aggL1_kernel<<<nbuck, 1024, 0, stream>>>(h1b, edata1, gcur, b1, W2, h2b, N);
    // ---- layer-2 aggregate + bias (in-LDS sort, 2-lane uint4 gathers)
    aggL2_kernel<<<nbuck, 512, 0, stream>>>(h2b, edata1, gcur, b2, out, N);
}

// Round 17
// 107.514 us; speedup vs baseline: 1.2955x; 1.0356x over previous
//
#include <hip/hip_runtime.h>

#define F_IN 128
#define F_H 64
#define F_OUT 16
#define RB 128           // nodes per bucket
#define RB_SHIFT 7       // bucket = dst >> 7
#define DBINS 64         // degree bins for bucket-local degree ranking
#define CAP 3072         // global bucket capacity (mean 2047, sigma 45)
#define LDSCAP 2816      // LDS sorted-edge capacity (mean + 17 sigma)
#define XSTR 136         // bf16 LDS row stride for gemm1 (16B-aligned b128)

typedef unsigned long long u64;
typedef unsigned int u32;
typedef unsigned short u16;
typedef __attribute__((ext_vector_type(8))) short short8;
typedef __attribute__((ext_vector_type(4))) float floatx4;

__device__ __forceinline__ u32 pack2bf16(float a, float b) {
    u32 ua = (__float_as_uint(a) + 0x8000u) >> 16;
    u32 ub = (__float_as_uint(b) + 0x8000u) & 0xFFFF0000u;
    return ua | ub;
}
__device__ __forceinline__ u16 bf16r(float a) {
    return (u16)((__float_as_uint(a) + 0x8000u) >> 16);
}

// ---------------------------------------------------------------------------
// GEMM1 (MFMA bf16): h1b[N,64](bf16 u32-pair rows) = x[N,128] @ W1[128,64]
// (R13 version, verbatim)
// ---------------------------------------------------------------------------
__global__ __launch_bounds__(256) void gemm1_kernel(
    const float* __restrict__ x, const float* __restrict__ W,
    u32* __restrict__ h1b, int N) {
    __shared__ u16 sh[2 * 64 * XSTR];    // 34.8 KB: xls | w1t; reused as f32 stage
    u16* xls = sh;
    u16* w1t = sh + 64 * XSTR;
    float* stage = (float*)sh;

    const int tid = threadIdx.x;
    const int n0 = blockIdx.x * 64;

    {   // load x tile -> bf16 LDS
        const int c4 = (tid & 31) * 4;
        const int r0 = tid >> 5;
        #pragma unroll
        for (int r = 0; r < 8; ++r) {
            const int row = r0 + r * 8;
            int n = n0 + row;
            if (n >= N) n = N - 1;
            const float4 v = *(const float4*)(x + (size_t)n * F_IN + c4);
            u16* p = &xls[row * XSTR + c4];
            p[0] = bf16r(v.x); p[1] = bf16r(v.y);
            p[2] = bf16r(v.z); p[3] = bf16r(v.w);
        }
    }
    {   // load W1 transposed -> bf16 LDS: w1t[col][k]
        const int k0 = tid >> 4;
        const int c4 = (tid & 15) * 4;
        #pragma unroll
        for (int r = 0; r < 8; ++r) {
            const int k = k0 + r * 16;
            const float4 v = *(const float4*)(W + (size_t)k * F_H + c4);
            w1t[(c4 + 0) * XSTR + k] = bf16r(v.x);
            w1t[(c4 + 1) * XSTR + k] = bf16r(v.y);
            w1t[(c4 + 2) * XSTR + k] = bf16r(v.z);
            w1t[(c4 + 3) * XSTR + k] = bf16r(v.w);
        }
    }
    __syncthreads();

    const int wv = tid >> 6;
    const int l = tid & 63;
    const int lr = l & 15;
    const int lk = (l >> 4) * 8;

    floatx4 acc[4] = {{0.f, 0.f, 0.f, 0.f}, {0.f, 0.f, 0.f, 0.f},
                      {0.f, 0.f, 0.f, 0.f}, {0.f, 0.f, 0.f, 0.f}};
    #pragma unroll
    for (int ks = 0; ks < 4; ++ks) {
        const short8 a = *(const short8*)&xls[(wv * 16 + lr) * XSTR + ks * 32 + lk];
        #pragma unroll
        for (int c = 0; c < 4; ++c) {
            const short8 bfr = *(const short8*)&w1t[(c * 16 + lr) * XSTR + ks * 32 + lk];
            acc[c] = __builtin_amdgcn_mfma_f32_16x16x32_bf16(a, bfr, acc[c], 0, 0, 0);
        }
    }
    __syncthreads();

    // C layout (verified): col = lane&15, row = (lane>>4)*4 + reg
    #pragma unroll
    for (int c = 0; c < 4; ++c) {
        #pragma unroll
        for (int r = 0; r < 4; ++r) {
            const int row = wv * 16 + (l >> 4) * 4 + r;
            stage[row * 65 + c * 16 + lr] = acc[c][r];
        }
    }
    __syncthreads();

    #pragma unroll
    for (int t = 0; t < 8; ++t) {
        const int idx = t * 256 + tid;
        const int row = idx >> 5, j = idx & 31;
        const int n = n0 + row;
        if (n < N) {
            const float f0 = stage[row * 65 + 2 * j];
            const float f1 = stage[row * 65 + 2 * j + 1];
            h1b[(size_t)n * 32 + j] = pack2bf16(f0, f1);
        }
    }
}

// ---------------------------------------------------------------------------
// fill: block-local counting sort into CAP-strided bucket-grouped edata1
// entry: [63:32]=weight f32 bits, [26:20]=dst&127, [19:0]=src
// (R13 version, verbatim)
// ---------------------------------------------------------------------------
__global__ __launch_bounds__(1024) void fill_kernel(
    const int* __restrict__ src, const int* __restrict__ dst,
    const float* __restrict__ ew, int* __restrict__ gcur,
    u64* __restrict__ edata, int E, int nbuck) {
    __shared__ int cnt[800];
    __shared__ int base[800];
    int chunk = (E + gridDim.x - 1) / gridDim.x;
    chunk = (chunk + 3) & ~3;
    const int e0 = blockIdx.x * chunk;
    const int e1 = min(e0 + chunk, E);

    for (int i = threadIdx.x; i < nbuck; i += 1024) cnt[i] = 0;
    __syncthreads();

    int e = e0 + threadIdx.x * 4;
    for (; e + 3 < e1; e += 4096) {
        const int4 d4 = *(const int4*)(dst + e);
        atomicAdd(&cnt[d4.x >> RB_SHIFT], 1);
        atomicAdd(&cnt[d4.y >> RB_SHIFT], 1);
        atomicAdd(&cnt[d4.z >> RB_SHIFT], 1);
        atomicAdd(&cnt[d4.w >> RB_SHIFT], 1);
    }
    for (; e < e1; ++e) atomicAdd(&cnt[dst[e] >> RB_SHIFT], 1);
    __syncthreads();

    for (int i = threadIdx.x; i < nbuck; i += 1024) {
        const int c = cnt[i];
        base[i] = i * CAP + (c ? atomicAdd(&gcur[i], c) : 0);
        cnt[i] = 0;
    }
    __syncthreads();

    e = e0 + threadIdx.x * 4;
    for (; e + 3 < e1; e += 4096) {
        const int4 d4 = *(const int4*)(dst + e);
        const int4 s4 = *(const int4*)(src + e);
        const float4 w4 = *(const float4*)(ew + e);
        {
            const int b = d4.x >> RB_SHIFT;
            const int p = atomicAdd(&cnt[b], 1);
            edata[(size_t)base[b] + p] = ((u64)__float_as_uint(w4.x) << 32) |
                (u32)s4.x | ((u32)(d4.x & (RB - 1)) << 20);
        }
        {
            const int b = d4.y >> RB_SHIFT;
            const int p = atomicAdd(&cnt[b], 1);
            edata[(size_t)base[b] + p] = ((u64)__float_as_uint(w4.y) << 32) |
                (u32)s4.y | ((u32)(d4.y & (RB - 1)) << 20);
        }
        {
            const int b = d4.z >> RB_SHIFT;
            const int p = atomicAdd(&cnt[b], 1);
            edata[(size_t)base[b] + p] = ((u64)__float_as_uint(w4.z) << 32) |
                (u32)s4.z | ((u32)(d4.z & (RB - 1)) << 20);
        }
        {
            const int b = d4.w >> RB_SHIFT;
            const int p = atomicAdd(&cnt[b], 1);
            edata[(size_t)base[b] + p] = ((u64)__float_as_uint(w4.w) << 32) |
                (u32)s4.w | ((u32)(d4.w & (RB - 1)) << 20);
        }
    }
    for (; e < e1; ++e) {
        const int d = dst[e];
        const int b = d >> RB_SHIFT;
        const int p = atomicAdd(&cnt[b], 1);
        edata[(size_t)base[b] + p] = ((u64)__float_as_uint(ew[e]) << 32) |
            (u32)src[e] | ((u32)(d & (RB - 1)) << 20);
    }
}

// ---------------------------------------------------------------------------
// aggL1: one 1024-thread block per bucket (R13 aggregation), with LDS-staged
// sort: edata read ONCE into esh0 while counting, then LDS->LDS scatter.
// ---------------------------------------------------------------------------
__global__ __launch_bounds__(1024) void aggL1_kernel(
    const u32* __restrict__ h1b, const u64* __restrict__ edata,
    const int* __restrict__ gcnt, const float* __restrict__ b1,
    const float* __restrict__ W2, u32* __restrict__ h2b, int N) {
    __shared__ u64 esh0[LDSCAP];         // 22.5 KB raw edges; reused as staging
    __shared__ u64 esh[LDSCAP];          // 22.5 KB sorted edges
    __shared__ float w2s[64 * 16];       // 4 KB
    __shared__ int cnt[RB];
    __shared__ int pref[RB];
    __shared__ int cur[RB];
    __shared__ int dbin[DBINS];
    __shared__ int dcur[DBINS];
    __shared__ int nodeOrder[RB];

    const int tid = threadIdx.x;
    const int b = blockIdx.x;
    const size_t s0 = (size_t)b * CAP;
    const int ecount = min(gcnt[b], LDSCAP);

    w2s[tid] = W2[tid];
    if (tid < RB) cnt[tid] = 0;
    if (tid < DBINS) dbin[tid] = 0;
    __syncthreads();

    // pass A: single global read -> esh0, count per node
    for (int i = tid; i < ecount; i += 1024) {
        const u64 ed = edata[s0 + i];
        esh0[i] = ed;
        atomicAdd(&cnt[((u32)ed >> 20) & (RB - 1)], 1);
    }
    __syncthreads();
    if (tid < RB) pref[tid] = cnt[tid];
    __syncthreads();
    for (int o = 1; o < RB; o <<= 1) {
        int v = 0;
        if (tid < RB && tid >= o) v = pref[tid - o];
        __syncthreads();
        if (tid < RB) pref[tid] += v;
        __syncthreads();
    }
    if (tid < RB) {
        cur[tid] = pref[tid] - cnt[tid];
        atomicAdd(&dbin[min(cnt[tid], DBINS - 1)], 1);
    }
    __syncthreads();
    if (tid < DBINS) dcur[tid] = dbin[tid];
    __syncthreads();
    for (int o = 1; o < DBINS; o <<= 1) {
        int v = 0;
        if (tid < DBINS && tid >= o) v = dcur[tid - o];
        __syncthreads();
        if (tid < DBINS) dcur[tid] += v;
        __syncthreads();
    }
    if (tid < DBINS) dcur[tid] -= dbin[tid];
    __syncthreads();
    if (tid < RB) {
        const int r = atomicAdd(&dcur[min(cnt[tid], DBINS - 1)], 1);
        nodeOrder[r] = tid;
    }
    // pass B: LDS->LDS scatter into node-sorted order
    for (int i = tid; i < ecount; i += 1024) {
        const u64 ed = esh0[i];
        const int d = ((u32)ed >> 20) & (RB - 1);
        const int p = atomicAdd(&cur[d], 1);
        esh[p] = ed;
    }
    __syncthreads();

    // gather: group g (8 lanes) = degree rank g (one node)
    const int g = tid >> 3;
    const int l = tid & 7;
    const int ln = nodeOrder[g];
    const int end = pref[ln];
    int i = end - cnt[ln];

    float acc[8];
    {
        const float4 ba = *(const float4*)(b1 + 8 * l);
        const float4 bb = *(const float4*)(b1 + 8 * l + 4);
        acc[0] = ba.x; acc[1] = ba.y; acc[2] = ba.z; acc[3] = ba.w;
        acc[4] = bb.x; acc[5] = bb.y; acc[6] = bb.z; acc[7] = bb.w;
    }
    for (; i + 4 <= end; i += 4) {
        u64 e[4];
        uint4 v[4];
        #pragma unroll
        for (int j = 0; j < 4; ++j) e[j] = esh[i + j];
        #pragma unroll
        for (int j = 0; j < 4; ++j)
            v[j] = *(const uint4*)(h1b + (size_t)((u32)e[j] & 0xFFFFF) * 32 + l * 4);
        #pragma unroll
        for (int j = 0; j < 4; ++j) {
            const float w = __uint_as_float((u32)(e[j] >> 32));
            acc[0] += __uint_as_float(v[j].x << 16) * w;
            acc[1] += __uint_as_float(v[j].x & 0xFFFF0000u) * w;
            acc[2] += __uint_as_float(v[j].y << 16) * w;
            acc[3] += __uint_as_float(v[j].y & 0xFFFF0000u) * w;
            acc[4] += __uint_as_float(v[j].z << 16) * w;
            acc[5] += __uint_as_float(v[j].z & 0xFFFF0000u) * w;
            acc[6] += __uint_as_float(v[j].w << 16) * w;
            acc[7] += __uint_as_float(v[j].w & 0xFFFF0000u) * w;
        }
    }
    for (; i < end; ++i) {
        const u64 e0 = esh[i];
        const float w0 = __uint_as_float((u32)(e0 >> 32));
        const uint4 v0 = *(const uint4*)(h1b + (size_t)((u32)e0 & 0xFFFFF) * 32 + l * 4);
        acc[0] += __uint_as_float(v0.x << 16) * w0;
        acc[1] += __uint_as_float(v0.x & 0xFFFF0000u) * w0;
        acc[2] += __uint_as_float(v0.y << 16) * w0;
        acc[3] += __uint_as_float(v0.y & 0xFFFF0000u) * w0;
        acc[4] += __uint_as_float(v0.z << 16) * w0;
        acc[5] += __uint_as_float(v0.z & 0xFFFF0000u) * w0;
        acc[6] += __uint_as_float(v0.w << 16) * w0;
        acc[7] += __uint_as_float(v0.w & 0xFFFF0000u) * w0;
    }

    // relu + pack to bf16, stage into esh0 (free after pass B)
    u32 pk[4];
    #pragma unroll
    for (int j = 0; j < 4; ++j)
        pk[j] = pack2bf16(fmaxf(acc[2 * j], 0.f), fmaxf(acc[2 * j + 1], 0.f));

    u32* stg = (u32*)esh0;               // 128 * 32 u32 = 16 KB
    #pragma unroll
    for (int j = 0; j < 4; ++j) stg[g * 32 + l * 4 + j] = pk[j];
    __syncthreads();

    // W2 pass: slot s = tid>>3 (rank), col pair c = tid&7 (cols 2c, 2c+1)
    const int s = tid >> 3;
    const int c = tid & 7;
    float o0 = 0.f, o1 = 0.f;
    #pragma unroll 8
    for (int w = 0; w < 32; ++w) {
        const u32 pw = stg[s * 32 + w];
        const float f0 = __uint_as_float(pw << 16);
        const float f1 = __uint_as_float(pw & 0xFFFF0000u);
        o0 += f0 * w2s[(2 * w) * 16 + 2 * c] + f1 * w2s[(2 * w + 1) * 16 + 2 * c];
        o1 += f0 * w2s[(2 * w) * 16 + 2 * c + 1] + f1 * w2s[(2 * w + 1) * 16 + 2 * c + 1];
    }
    const int gn = b * RB + nodeOrder[s];
    if (gn < N) h2b[(size_t)gn * 8 + c] = pack2bf16(o0, o1);
}

// ---------------------------------------------------------------------------
// aggL2: one 1024-thread block per bucket.
//  LDS-staged sort (single global edata read), degree rank; then 128 groups
//  x 8 lanes: 4 edge-slots x 2 row-halves, shfl_xor(2,4) combine -> out.
// ---------------------------------------------------------------------------
__global__ __launch_bounds__(1024) void aggL2_kernel(
    const u32* __restrict__ h2b, const u64* __restrict__ edata,
    const int* __restrict__ gcnt, const float* __restrict__ b2,
    float* __restrict__ out, int N) {
    __shared__ u64 esh0[LDSCAP];
    __shared__ u64 esh[LDSCAP];
    __shared__ int cnt[RB];
    __shared__ int pref[RB];
    __shared__ int cur[RB];
    __shared__ int dbin[DBINS];
    __shared__ int dcur[DBINS];
    __shared__ int nodeOrder[RB];

    const int tid = threadIdx.x;
    const int b = blockIdx.x;
    const size_t s0 = (size_t)b * CAP;
    const int ecount = min(gcnt[b], LDSCAP);

    if (tid < RB) cnt[tid] = 0;
    if (tid < DBINS) dbin[tid] = 0;
    __syncthreads();

    for (int i = tid; i < ecount; i += 1024) {
        const u64 ed = edata[s0 + i];
        esh0[i] = ed;
        atomicAdd(&cnt[((u32)ed >> 20) & (RB - 1)], 1);
    }
    __syncthreads();
    if (tid < RB) pref[tid] = cnt[tid];
    __syncthreads();
    for (int o = 1; o < RB; o <<= 1) {
        int v = 0;
        if (tid < RB && tid >= o) v = pref[tid - o];
        __syncthreads();
        if (tid < RB) pref[tid] += v;
        __syncthreads();
    }
    if (tid < RB) {
        cur[tid] = pref[tid] - cnt[tid];
        atomicAdd(&dbin[min(cnt[tid], DBINS - 1)], 1);
    }
    __syncthreads();
    if (tid < DBINS) dcur[tid] = dbin[tid];
    __syncthreads();
    for (int o = 1; o < DBINS; o <<= 1) {
        int v = 0;
        if (tid < DBINS && tid >= o) v = dcur[tid - o];
        __syncthreads();
        if (tid < DBINS) dcur[tid] += v;
        __syncthreads();
    }
    if (tid < DBINS) dcur[tid] -= dbin[tid];
    __syncthreads();
    if (tid < RB) {
        const int r = atomicAdd(&dcur[min(cnt[tid], DBINS - 1)], 1);
        nodeOrder[r] = tid;
    }
    __syncthreads();
    for (int i = tid; i < ecount; i += 1024) {
        const u64 ed = esh0[i];
        const int d = ((u32)ed >> 20) & (RB - 1);
        const int p = atomicAdd(&cur[d], 1);
        esh[p] = ed;
    }
    __syncthreads();

    // gather: group g (8 lanes) = degree rank g; esub = edge slot, half = 16B
    const int g = tid >> 3;
    const int l = tid & 7;
    const int esub = l >> 1;
    const int half = l & 1;
    const int ln = nodeOrder[g];
    const int gn = b * RB + ln;
    const int end = pref[ln];
    const int beg = end - cnt[ln];

    float acc[8] = {0.f, 0.f, 0.f, 0.f, 0.f, 0.f, 0.f, 0.f};
    int i = beg + esub;
    for (; i + 4 < end; i += 8) {        // 2 edges in flight per lane
        const u64 e0 = esh[i];
        const u64 e1 = esh[i + 4];
        const float w0 = __uint_as_float((u32)(e0 >> 32));
        const float w1 = __uint_as_float((u32)(e1 >> 32));
        const uint4 v0 = *(const uint4*)(h2b + (size_t)((u32)e0 & 0xFFFFF) * 8 + half * 4);
        const uint4 v1 = *(const uint4*)(h2b + (size_t)((u32)e1 & 0xFFFFF) * 8 + half * 4);
        acc[0] += __uint_as_float(v0.x << 16) * w0 + __uint_as_float(v1.x << 16) * w1;
        acc[1] += __uint_as_float(v0.x & 0xFFFF0000u) * w0 + __uint_as_float(v1.x & 0xFFFF0000u) * w1;
        acc[2] += __uint_as_float(v0.y << 16) * w0 + __uint_as_float(v1.y << 16) * w1;
        acc[3] += __uint_as_float(v0.y & 0xFFFF0000u) * w0 + __uint_as_float(v1.y & 0xFFFF0000u) * w1;
        acc[4] += __uint_as_float(v0.z << 16) * w0 + __uint_as_float(v1.z << 16) * w1;
        acc[5] += __uint_as_float(v0.z & 0xFFFF0000u) * w0 + __uint_as_float(v1.z & 0xFFFF0000u) * w1;
        acc[6] += __uint_as_float(v0.w << 16) * w0 + __uint_as_float(v1.w << 16) * w1;
        acc[7] += __uint_as_float(v0.w & 0xFFFF0000u) * w0 + __uint_as_float(v1.w & 0xFFFF0000u) * w1;
    }
    if (i < end) {
        const u64 e0 = esh[i];
        const float w0 = __uint_as_float((u32)(e0 >> 32));
        const uint4 v0 = *(const uint4*)(h2b + (size_t)((u32)e0 & 0xFFFFF) * 8 + half * 4);
        acc[0] += __uint_as_float(v0.x << 16) * w0;
        acc[1] += __uint_as_float(v0.x & 0xFFFF0000u) * w0;
        acc[2] += __uint_as_float(v0.y << 16) * w0;
        acc[3] += __uint_as_float(v0.y & 0xFFFF0000u) * w0;
        acc[4] += __uint_as_float(v0.z << 16) * w0;
        acc[5] += __uint_as_float(v0.z & 0xFFFF0000u) * w0;
        acc[6] += __uint_as_float(v0.w << 16) * w0;
        acc[7] += __uint_as_float(v0.w & 0xFFFF0000u) * w0;
    }
    // combine edge slots (lanes differing in bits 1-2; same half)
    #pragma unroll
    for (int k = 0; k < 8; ++k) {
        acc[k] += __shfl_xor(acc[k], 2, 64);
        acc[k] += __shfl_xor(acc[k], 4, 64);
    }
    if (esub == 0 && gn < N) {
        const float4 ba = *(const float4*)(b2 + 8 * half);
        const float4 bb = *(const float4*)(b2 + 8 * half + 4);
        float* p = out + (size_t)gn * F_OUT + 8 * half;
        *(float4*)(p + 0) = make_float4(acc[0] + ba.x, acc[1] + ba.y,
                                        acc[2] + ba.z, acc[3] + ba.w);
        *(float4*)(p + 4) = make_float4(acc[4] + bb.x, acc[5] + bb.y,
                                        acc[6] + bb.z, acc[7] + bb.w);
    }
}

extern "C" void kernel_launch(void* const* d_in, const int* in_sizes, int n_in,
                              void* d_out, int out_size, void* d_ws, size_t ws_size,
                              hipStream_t stream) {
    const float* x   = (const float*)d_in[0];
    const int*   src = (const int*)d_in[1];
    const int*   dst = (const int*)d_in[2];
    const float* ew  = (const float*)d_in[3];
    const float* W1  = (const float*)d_in[4];
    const float* b1  = (const float*)d_in[5];
    const float* W2  = (const float*)d_in[6];
    const float* b2  = (const float*)d_in[7];
    float* out = (float*)d_out;

    const int N = in_sizes[0] / F_IN;            // 100000
    const int E = in_sizes[1];                   // 1600000
    const int nbuck = (N + RB - 1) >> RB_SHIFT;  // 782

    char* base = (char*)d_ws;
    auto align256 = [](size_t v) { return (v + 255) & ~(size_t)255; };
    size_t oH1  = 0;
    size_t oED1 = align256(oH1  + (size_t)N * 32 * 4);       // h1b bf16 12.8MB
    size_t oH2B = align256(oED1 + (size_t)nbuck * CAP * 8);  // edata1 19.2MB
    size_t oCUR = align256(oH2B + (size_t)N * 8 * 4);        // h2b bf16 3.2MB
    (void)ws_size;

    u32*   h1b    = (u32*)(base + oH1);
    u64*   edata1 = (u64*)(base + oED1);
    u32*   h2b    = (u32*)(base + oH2B);
    int*   gcur   = (int*)(base + oCUR);

    // ---- preprocessing: CAP-strided bucket fill (counts end up in gcur)
    hipMemsetAsync(gcur, 0, (size_t)nbuck * 4, stream);
    fill_kernel<<<128, 1024, 0, stream>>>(src, dst, ew, gcur, edata1, E, nbuck);

    // ---- layer 1 transform (MFMA bf16)
    gemm1_kernel<<<(N + 63) / 64, 256, 0, stream>>>(x, W1, h1b, N);
    // ---- layer-1 aggregate + relu + W2 (LDS-staged sort) -> h2b bf16
    aggL1_kernel<<<nbuck, 1024, 0, stream>>>(h1b, edata1, gcur, b1, W2, h2b, N);
    // ---- layer-2 aggregate + bias (LDS-staged sort, 8-lane groups)
    aggL2_kernel<<<nbuck, 1024, 0, stream>>>(h2b, edata1, gcur, b2, out, N);
}